// Round 4
// baseline (1823.061 us; speedup 1.0000x reference)
//
#include <hip/hip_runtime.h>
#include <math.h>

#define DM   272
#define DS   32
#define DI   544
#define DTR  17
#define SEQL 512
#define NB   2
#define ROWS 1024
#define DXZ  1088
#define NL   12

// workspace offsets (in floats)
#define OFF_X     0          // 1024*272
#define OFF_INVR  278528     // 1024
#define OFF_XZ    279552     // 4*512*1088 = 2228224
#define OFF_XCT   2507776    // 4*544*512  = 1114112  (channel-major)
#define OFF_DTT   3621888    // 4*544*512
#define OFF_ZT    4736000    // 4*544*512
#define OFF_BM    5850112    // 4*512*32 = 65536
#define OFF_CM    5915648    // 4*512*32
#define OFF_YOT   5981184    // 4*544*512  (channel-major)
#define OFF_Y12   7095296    // 2*1024*272 = 557056
#define OFF_XMP   7652352    // 16*272
#define OFF_DTWT  7656704    // 24*17*544  = 221952
// end: 7,878,656 floats = 31.5 MB

__device__ __forceinline__ float sigmoid_fast(float x){ return 1.f/(1.f+__expf(-x)); }
__device__ __forceinline__ float softplus_f(float x){ return (x > 20.f) ? x : log1pf(__expf(x)); }

__device__ __forceinline__ float block_reduce_256(float v, volatile float* sred, int tid){
#pragma unroll
  for (int m=32; m>=1; m>>=1) v += __shfl_xor(v, m);
  __syncthreads();
  if ((tid & 63) == 0) sred[tid>>6] = v;
  __syncthreads();
  return sred[0]+sred[1]+sred[2]+sred[3];
}

// ---------------------------------------------------------------- init
__global__ __launch_bounds__(64) void k_init(const float* __restrict__ x0,
                                             float* __restrict__ xb, float* __restrict__ invr){
  int r = blockIdx.x, tid = threadIdx.x;
  float ss = 0.f;
  for (int c=tid; c<DM; c+=64){ float v = x0[(size_t)r*DM+c]; xb[(size_t)r*DM+c]=v; ss += v*v; }
#pragma unroll
  for (int m=32;m>=1;m>>=1) ss += __shfl_xor(ss,m);
  if (tid==0) invr[r] = rsqrtf(ss*(1.f/DM)+1e-5f);
}

// ---------------------------------------------------------------- dt_proj weight transpose
// dtw [24][544][17] -> dtwT [24][17][544]
__global__ __launch_bounds__(256) void k_transpose(const float* __restrict__ dtw,
                                                   float* __restrict__ dtwT){
  int idx = blockIdx.x*256 + threadIdx.x;
  const int T2 = 24*544*DTR;
  if (idx < T2){
    int ld = idx / (544*DTR); int rem = idx - ld*(544*DTR);
    int d = rem / DTR; int r = rem - d*DTR;
    dtwT[(size_t)ld*DTR*544 + (size_t)r*544 + d] = dtw[idx];
  }
}

// ---------------------------------------------------------------- in_proj GEMM (rmsnorm fused)
__global__ __launch_bounds__(256) void k_inproj(
    const float* __restrict__ xb, const float* __restrict__ invr,
    const float* __restrict__ n1w, const float* __restrict__ inw,
    float* __restrict__ xz)
{
  __shared__ float As[16][76];
  __shared__ float Bs[16][76];
  const int tid = threadIdx.x;
  const int m0 = blockIdx.x << 6;
  const int nt = blockIdx.y;                    // 0..33
  const int dir = (nt >= 17) ? 1 : 0;
  const int n0l = (nt - dir*17) << 6;
  const float* wb = inw + (size_t)(dir*1088 + n0l)*272;
  const int tr = tid & 15, tc = tid >> 4;
  const int lr = tid >> 2, lk = (tid & 3) << 2;
  const float ivr = invr[m0 + lr];
  const float* xrow = xb + (size_t)(m0 + lr)*272;
  const float* wrow = wb + (size_t)lr*272;
  float acc[4][4];
#pragma unroll
  for (int i=0;i<4;i++)
#pragma unroll
    for (int j=0;j<4;j++) acc[i][j]=0.f;
  for (int k0=0;k0<272;k0+=16){
    float4 a4 = *(const float4*)(xrow + k0 + lk);
    float4 g4 = *(const float4*)(n1w + k0 + lk);
    float4 b4 = *(const float4*)(wrow + k0 + lk);
    As[lk+0][lr] = a4.x*ivr*g4.x;
    As[lk+1][lr] = a4.y*ivr*g4.y;
    As[lk+2][lr] = a4.z*ivr*g4.z;
    As[lk+3][lr] = a4.w*ivr*g4.w;
    Bs[lk+0][lr] = b4.x; Bs[lk+1][lr]=b4.y; Bs[lk+2][lr]=b4.z; Bs[lk+3][lr]=b4.w;
    __syncthreads();
#pragma unroll
    for (int kk=0;kk<16;kk++){
      float4 av = *(const float4*)(&As[kk][tr<<2]);
      float4 bv = *(const float4*)(&Bs[kk][tc<<2]);
      acc[0][0]+=av.x*bv.x; acc[0][1]+=av.x*bv.y; acc[0][2]+=av.x*bv.z; acc[0][3]+=av.x*bv.w;
      acc[1][0]+=av.y*bv.x; acc[1][1]+=av.y*bv.y; acc[1][2]+=av.y*bv.z; acc[1][3]+=av.y*bv.w;
      acc[2][0]+=av.z*bv.x; acc[2][1]+=av.z*bv.y; acc[2][2]+=av.z*bv.z; acc[2][3]+=av.z*bv.w;
      acc[3][0]+=av.w*bv.x; acc[3][1]+=av.w*bv.y; acc[3][2]+=av.w*bv.z; acc[3][3]+=av.w*bv.w;
    }
    __syncthreads();
  }
#pragma unroll
  for (int i=0;i<4;i++){
    int r = m0 + (tr<<2) + i;
    int b = r >> 9, t = r & 511;
    int ts = dir ? (511 - t) : t;
    float4 v = make_float4(acc[i][0],acc[i][1],acc[i][2],acc[i][3]);
    *(float4*)(xz + (size_t)((dir*NB + b)*SEQL + ts)*DXZ + n0l + (tc<<2)) = v;
  }
}

// ---------------------------------------------------------------- conv4+silu + x_proj + dt_proj
// block = 4 rows, grid 512; x_proj e-major (weights from original [e][544] rows)
__global__ __launch_bounds__(256) void k_xdt(
  const float* __restrict__ xz, const float* __restrict__ cwl, const float* __restrict__ cbl,
  const float* __restrict__ xwl, const float* __restrict__ dtwTl, const float* __restrict__ dtbl,
  float* __restrict__ xcT, float* __restrict__ dtT, float* __restrict__ zT,
  float* __restrict__ Bmg, float* __restrict__ Cmg)
{
  __shared__ float xcs[4][548];
  __shared__ float part[3][4][81];
  __shared__ float dts[4][DTR];
  const int tid = threadIdx.x;
  const int blk = blockIdx.x;        // 0..511
  const int seg = blk >> 7;          // dir*2 + b
  const int dir = seg >> 1;
  const int t0 = (blk & 127) << 2;
  const float* xzb  = xz + (size_t)seg*SEQL*DXZ;
  const float* cw   = cwl + dir*DI*4;
  const float* cb   = cbl + dir*DI;
  const float* xw   = xwl + (size_t)dir*81*DI;   // [e][544] rows
  const float* dtwT = dtwTl + (size_t)dir*DTR*DI;
  const float* dtb  = dtbl + dir*DI;
  const size_t chb = (size_t)seg*DI;  // channel-row base

  // phase 1: conv4 + silu (+ z extract), channel-major row stores
  for (int j = tid; j < DI; j += 256){
    float4 w4 = *(const float4*)(cw + j*4);
    float bj = cb[j];
    float xv[7];
#pragma unroll
    for (int q=0; q<7; q++){
      int t = t0 + q - 3;
      xv[q] = (t >= 0) ? xzb[(size_t)t*DXZ + j] : 0.f;
    }
    float xo[4], zo[4];
#pragma unroll
    for (int rr=0; rr<4; rr++){
      float acc = bj + w4.x*xv[rr] + w4.y*xv[rr+1] + w4.z*xv[rr+2] + w4.w*xv[rr+3];
      float v = acc * sigmoid_fast(acc);
      xcs[rr][j] = v; xo[rr] = v;
      zo[rr] = xzb[(size_t)(t0+rr)*DXZ + 544 + j];
    }
    *(float4*)(xcT + (chb + j)*SEQL + t0) = make_float4(xo[0],xo[1],xo[2],xo[3]);
    *(float4*)(zT  + (chb + j)*SEQL + t0) = make_float4(zo[0],zo[1],zo[2],zo[3]);
  }
  __syncthreads();

  // phase 2: x_proj — thread owns (e, k-slice); weights reused across 4 rows
  if (tid < 243){
    const int ks = tid / 81;
    const int e  = tid - ks*81;
    const int kb = (ks==0) ? 0 : (ks==1) ? 184 : 368;
    const int ke = (ks==0) ? 184 : (ks==1) ? 368 : 544;
    const float* wrow = xw + (size_t)e*DI;
    float a0=0.f, a1=0.f, a2=0.f, a3=0.f;
    for (int k=kb; k<ke; k+=4){
      float4 w4 = *(const float4*)(wrow + k);
      float4 x0 = *(const float4*)(&xcs[0][k]);
      float4 x1 = *(const float4*)(&xcs[1][k]);
      float4 x2 = *(const float4*)(&xcs[2][k]);
      float4 x3 = *(const float4*)(&xcs[3][k]);
      a0 = fmaf(w4.x,x0.x, fmaf(w4.y,x0.y, fmaf(w4.z,x0.z, fmaf(w4.w,x0.w, a0))));
      a1 = fmaf(w4.x,x1.x, fmaf(w4.y,x1.y, fmaf(w4.z,x1.z, fmaf(w4.w,x1.w, a1))));
      a2 = fmaf(w4.x,x2.x, fmaf(w4.y,x2.y, fmaf(w4.z,x2.z, fmaf(w4.w,x2.w, a2))));
      a3 = fmaf(w4.x,x3.x, fmaf(w4.y,x3.y, fmaf(w4.z,x3.z, fmaf(w4.w,x3.w, a3))));
    }
    part[ks][0][e]=a0; part[ks][1][e]=a1; part[ks][2][e]=a2; part[ks][3][e]=a3;
  }
  __syncthreads();
  for (int idx=tid; idx<324; idx+=256){
    int ta = idx / 81, e = idx - ta*81;
    float s = part[0][ta][e] + part[1][ta][e] + part[2][ta][e];
    size_t row = (size_t)seg*SEQL + t0 + ta;
    if (e < DTR)      dts[ta][e] = s;
    else if (e < 49)  Bmg[row*DS + (e-DTR)] = s;
    else              Cmg[row*DS + (e-49)] = s;
  }
  __syncthreads();

  // phase 3: dt_proj + softplus, channel-major row stores
  {
    const int c1 = tid, c2 = tid+256;
    const bool h3 = tid < 32; const int c3 = 512 + tid;
    float w1[DTR], w2[DTR], w3[DTR];
#pragma unroll
    for (int q=0; q<DTR; q++){
      w1[q] = dtwT[q*DI + c1];
      w2[q] = dtwT[q*DI + c2];
      w3[q] = h3 ? dtwT[q*DI + c3] : 0.f;
    }
    float b1 = dtb[c1], b2 = dtb[c2], b3 = h3 ? dtb[c3] : 0.f;
    float o1[4], o2[4], o3[4];
#pragma unroll
    for (int rr=0; rr<4; rr++){
      float a1=b1, a2=b2, a3=b3;
#pragma unroll
      for (int q=0; q<DTR; q++){
        float dv = dts[rr][q];
        a1 = fmaf(w1[q],dv,a1); a2 = fmaf(w2[q],dv,a2); a3 = fmaf(w3[q],dv,a3);
      }
      o1[rr]=softplus_f(a1); o2[rr]=softplus_f(a2); o3[rr]=softplus_f(a3);
    }
    *(float4*)(dtT + (chb + c1)*SEQL + t0) = make_float4(o1[0],o1[1],o1[2],o1[3]);
    *(float4*)(dtT + (chb + c2)*SEQL + t0) = make_float4(o2[0],o2[1],o2[2],o2[3]);
    if (h3)
      *(float4*)(dtT + (chb + c3)*SEQL + t0) = make_float4(o3[0],o3[1],o3[2],o3[3]);
  }
}

// ---------------------------------------------------------------- chunked selective scan + gate
__global__ __launch_bounds__(128) void k_scan(
  const float* __restrict__ dtT, const float* __restrict__ xcT,
  const float* __restrict__ Bmg, const float* __restrict__ Cmg,
  const float* __restrict__ alogl, const float* __restrict__ dskl,
  const float* __restrict__ zT, float* __restrict__ yoT)
{
  __shared__ float hl[16][33], pl[16][33], Hi[16][33];
  const int d = blockIdx.x, b = blockIdx.y, dir = blockIdx.z;
  const int seg = dir*NB + b;
  const int tid = threadIdx.x;
  const int c = tid >> 3, sg = tid & 7, s0 = sg << 2;
  float A0,A1,A2,A3;
  {
    const float* al = alogl + (size_t)(dir*DI + d)*DS + s0;
    A0 = -expf(al[0]); A1 = -expf(al[1]); A2 = -expf(al[2]); A3 = -expf(al[3]);
  }
  const size_t cr = ((size_t)seg*DI + d)*SEQL;
  const float* dtr = dtT + cr;
  const float* xcr = xcT + cr;
  const float* zr  = zT  + cr;
  float* yor = yoT + cr;
  const float* Bp = Bmg + (size_t)seg*SEQL*DS + s0;
  const float* Cp = Cmg + (size_t)seg*SEQL*DS + s0;
  float h0=0,h1=0,h2=0,h3=0,p0=1,p1=1,p2=1,p3=1;
  const int tb = c << 5;
  for (int tq=0; tq<8; tq++){
    const int t4 = tb + (tq<<2);
    float4 dt4 = *(const float4*)(dtr + t4);
    const float* dtp4 = (const float*)&dt4;
    float4 xc4 = *(const float4*)(xcr + t4);
    const float* xcp4 = (const float*)&xc4;
#pragma unroll
    for (int u=0; u<4; u++){
      float ldt = dtp4[u], lxc = xcp4[u];
      float4 B4 = *(const float4*)(Bp + (size_t)(t4+u)*DS);
      float uu = ldt*lxc;
      float e;
      e = __expf(ldt*A0); h0 = fmaf(e,h0,uu*B4.x); p0*=e;
      e = __expf(ldt*A1); h1 = fmaf(e,h1,uu*B4.y); p1*=e;
      e = __expf(ldt*A2); h2 = fmaf(e,h2,uu*B4.z); p2*=e;
      e = __expf(ldt*A3); h3 = fmaf(e,h3,uu*B4.w); p3*=e;
    }
  }
  hl[c][s0]=h0; hl[c][s0+1]=h1; hl[c][s0+2]=h2; hl[c][s0+3]=h3;
  pl[c][s0]=p0; pl[c][s0+1]=p1; pl[c][s0+2]=p2; pl[c][s0+3]=p3;
  __syncthreads();
  if (tid < 32){
    float H = 0.f;
    Hi[0][tid] = 0.f;
    for (int cc=1; cc<16; cc++){
      H = fmaf(pl[cc-1][tid], H, hl[cc-1][tid]);
      Hi[cc][tid] = H;
    }
  }
  __syncthreads();
  h0=Hi[c][s0]; h1=Hi[c][s0+1]; h2=Hi[c][s0+2]; h3=Hi[c][s0+3];
  const float dsk = dskl[dir*DI + d];
  for (int tq=0; tq<8; tq++){
    const int t4 = tb + (tq<<2);
    float4 dt4 = *(const float4*)(dtr + t4);
    const float* dtp4 = (const float*)&dt4;
    float4 xc4 = *(const float4*)(xcr + t4);
    const float* xcp4 = (const float*)&xc4;
    float4 z4 = *(const float4*)(zr + t4);
    const float* zp4 = (const float*)&z4;
    float yv[4];
#pragma unroll
    for (int u=0; u<4; u++){
      float ldt = dtp4[u], lxc = xcp4[u];
      float4 B4 = *(const float4*)(Bp + (size_t)(t4+u)*DS);
      float4 C4 = *(const float4*)(Cp + (size_t)(t4+u)*DS);
      float uu = ldt*lxc;
      float e;
      e = __expf(ldt*A0); h0 = fmaf(e,h0,uu*B4.x);
      e = __expf(ldt*A1); h1 = fmaf(e,h1,uu*B4.y);
      e = __expf(ldt*A2); h2 = fmaf(e,h2,uu*B4.z);
      e = __expf(ldt*A3); h3 = fmaf(e,h3,uu*B4.w);
      float y = h0*C4.x + h1*C4.y + h2*C4.z + h3*C4.w;
      y += __shfl_xor(y,1); y += __shfl_xor(y,2); y += __shfl_xor(y,4);
      float z = zp4[u];
      yv[u] = fmaf(dsk, lxc, y) * (z * sigmoid_fast(z));
    }
    if (sg==0) *(float4*)(yor + t4) = make_float4(yv[0],yv[1],yv[2],yv[3]);
  }
}

// ---------------------------------------------------------------- out_proj GEMM (A = yoT channel-major)
__global__ __launch_bounds__(128) void k_outproj(
    const float* __restrict__ yoT, const float* __restrict__ ow, float* __restrict__ y12)
{
  __shared__ float As[16][68];
  __shared__ float Bs[16][40];
  const int tid = threadIdx.x;
  const int m0 = blockIdx.x << 6;
  const int n0 = blockIdx.y << 5;
  const int dir = blockIdx.z;
  const int bseg = m0 >> 9;
  const int t0 = m0 & 511;
  const float* At = yoT + (size_t)(dir*NB + bseg)*DI*SEQL;
  const float* W = ow + (size_t)dir*DM*DI;
  const int smi = (tid & 15) << 2;
  const int skk = tid >> 4;
  const int lrb = tid >> 2, lkb = (tid & 3) << 2;
  const int tr = tid & 15, tc = tid >> 4;
  const int nb = n0 + lrb;
  const bool bvalid = nb < DM;
  const float* wrow = W + (size_t)(bvalid ? nb : 0)*DI;
  float acc[4][4];
#pragma unroll
  for (int i=0;i<4;i++)
#pragma unroll
    for (int j=0;j<4;j++) acc[i][j]=0.f;
  for (int k0=0;k0<544;k0+=16){
    float4 a0 = *(const float4*)(At + (size_t)(k0+skk)*SEQL + t0 + smi);
    float4 a1 = *(const float4*)(At + (size_t)(k0+skk+8)*SEQL + t0 + smi);
    *(float4*)(&As[skk][smi])   = a0;
    *(float4*)(&As[skk+8][smi]) = a1;
    float4 b4 = bvalid ? *(const float4*)(wrow + k0 + lkb) : make_float4(0.f,0.f,0.f,0.f);
    Bs[lkb+0][lrb]=b4.x; Bs[lkb+1][lrb]=b4.y; Bs[lkb+2][lrb]=b4.z; Bs[lkb+3][lrb]=b4.w;
    __syncthreads();
#pragma unroll
    for (int kk=0;kk<16;kk++){
      float4 av = *(const float4*)(&As[kk][tr<<2]);
      float4 bv = *(const float4*)(&Bs[kk][tc<<2]);
      acc[0][0]+=av.x*bv.x; acc[0][1]+=av.x*bv.y; acc[0][2]+=av.x*bv.z; acc[0][3]+=av.x*bv.w;
      acc[1][0]+=av.y*bv.x; acc[1][1]+=av.y*bv.y; acc[1][2]+=av.y*bv.z; acc[1][3]+=av.y*bv.w;
      acc[2][0]+=av.z*bv.x; acc[2][1]+=av.z*bv.y; acc[2][2]+=av.z*bv.z; acc[2][3]+=av.z*bv.w;
      acc[3][0]+=av.w*bv.x; acc[3][1]+=av.w*bv.y; acc[3][2]+=av.w*bv.z; acc[3][3]+=av.w*bv.w;
    }
    __syncthreads();
  }
  int col = n0 + (tc<<2);
  if (col < DM){
#pragma unroll
    for (int i=0;i<4;i++){
      int r = m0 + (tr<<2) + i;
      int b = r >> 9, t = r & 511;
      int ts = dir ? (511 - t) : t;
      float4 v = make_float4(acc[i][0],acc[i][1],acc[i][2],acc[i][3]);
      *(float4*)(y12 + (size_t)dir*ROWS*DM + (size_t)(b*SEQL+ts)*DM + col) = v;
    }
  }
}

// ---------------------------------------------------------------- combine
__global__ __launch_bounds__(256) void k_combine(
  const float* __restrict__ y12, const float* __restrict__ lamq,
  const float* __restrict__ n2w, float* __restrict__ xb,
  float* __restrict__ invr, float lam_init, float omli)
{
  __shared__ float sred[4];
  const int tid = threadIdx.x;
  const int r = blockIdx.x;
  const float* y1 = y12 + (size_t)r*DM;
  const float* y2 = y12 + (size_t)ROWS*DM + (size_t)r*DM;
  float lp = lamq[tid];
  if (tid < 16) lp += lamq[tid+256];
  float lsum = block_reduce_256(lp, sred, tid);
  float lam = sigmoid_fast(lsum) + lam_init;
  float a0 = y1[tid] - lam*y2[tid];
  float a1 = 0.f;
  if (tid<16) a1 = y1[tid+256] - lam*y2[tid+256];
  float ss = block_reduce_256(a0*a0 + a1*a1, sred, tid);
  float rms = rsqrtf(ss*(1.f/DM) + 1e-5f);
  float xo0 = xb[(size_t)r*DM + tid] + a0*rms*n2w[tid]*omli;
  float xo1 = 0.f;
  if (tid<16) xo1 = xb[(size_t)r*DM + tid+256] + a1*rms*n2w[tid+256]*omli;
  xb[(size_t)r*DM+tid] = xo0;
  if (tid<16) xb[(size_t)r*DM+tid+256] = xo1;
  float ss2 = block_reduce_256(xo0*xo0 + xo1*xo1, sred, tid);
  if (tid==0) invr[r] = rsqrtf(ss2*(1.f/DM) + 1e-5f);
}

// ---------------------------------------------------------------- head
__global__ __launch_bounds__(256) void k_head1(const float* __restrict__ xb, float* __restrict__ xmp){
  int ch = blockIdx.x, b = blockIdx.y, tid = threadIdx.x;
  int t0 = ch*64;
  float s0=0.f, s1=0.f;
  for (int t=t0; t<t0+64; t++){
    const float* row = xb + (size_t)(b*SEQL+t)*DM;
    s0 += row[tid];
    if (tid<16) s1 += row[tid+256];
  }
  xmp[(size_t)(b*8+ch)*DM + tid] = s0;
  if (tid<16) xmp[(size_t)(b*8+ch)*DM + tid+256] = s1;
}

__global__ __launch_bounds__(256) void k_head2(
  const float* __restrict__ xmp, const float* __restrict__ yin,
  const float* __restrict__ mlpw, const float* __restrict__ mlpb,
  const float* __restrict__ pw, const float* __restrict__ pb,
  float* __restrict__ out)
{
  __shared__ float xm[2][DM];
  __shared__ float x2s[2][DM];
  __shared__ float sred[4];
  int tid = threadIdx.x;
  for (int idx=tid; idx<2*DM; idx+=256){
    int b = idx / DM, c = idx - b*DM;
    float s=0.f;
    for (int ch=0; ch<8; ch++) s += xmp[(size_t)(b*8+ch)*DM + c];
    xm[b][c] = s * (1.f/SEQL);
  }
  __syncthreads();
  for (int idx=tid; idx<2*DM; idx+=256){
    int b = idx / DM, c = idx - b*DM;
    float acc = mlpb[c];
    const float* wr = mlpw + (size_t)c*DM;
    for (int k=0;k<DM;k++) acc += wr[k]*xm[b][k];
    float v = fmaxf(acc, 0.f);
    x2s[b][c] = v;
    out[2 + b*DM + c] = v;
  }
  __syncthreads();
  for (int b=0;b<2;b++){
    float p = x2s[b][tid]*pw[tid];
    if (tid<16) p += x2s[b][tid+256]*pw[tid+256];
    float tot = block_reduce_256(p, sred, tid);
    if (tid==0) out[b] = tot + yin[b]*pw[DM] + pb[0];
  }
}

// ----------------------------------------------------------------
extern "C" void kernel_launch(void* const* d_in, const int* in_sizes, int n_in,
                              void* d_out, int out_size, void* d_ws, size_t ws_size,
                              hipStream_t stream)
{
  const float* x0     = (const float*)d_in[0];
  const float* yin    = (const float*)d_in[1];
  const float* in_w   = (const float*)d_in[2];
  const float* conv_w = (const float*)d_in[3];
  const float* conv_b = (const float*)d_in[4];
  const float* x_w    = (const float*)d_in[5];
  const float* dt_w   = (const float*)d_in[6];
  const float* dt_b   = (const float*)d_in[7];
  const float* a_log  = (const float*)d_in[8];
  const float* dskip  = (const float*)d_in[9];
  const float* out_w  = (const float*)d_in[10];
  const float* lamq   = (const float*)d_in[11];
  const float* n1w    = (const float*)d_in[12];
  const float* n2w    = (const float*)d_in[13];
  const float* mlpw   = (const float*)d_in[14];
  const float* mlpb   = (const float*)d_in[15];
  const float* pw     = (const float*)d_in[16];
  const float* pb     = (const float*)d_in[17];

  float* ws  = (float*)d_ws;
  float* xb  = ws + OFF_X;
  float* invr= ws + OFF_INVR;
  float* xz  = ws + OFF_XZ;
  float* xcT = ws + OFF_XCT;
  float* dtT = ws + OFF_DTT;
  float* zT  = ws + OFF_ZT;
  float* Bm  = ws + OFF_BM;
  float* Cm  = ws + OFF_CM;
  float* yoT = ws + OFF_YOT;
  float* y12 = ws + OFF_Y12;
  float* xmp = ws + OFF_XMP;
  float* dtwT= ws + OFF_DTWT;
  float* outp = (float*)d_out;

  k_transpose<<<(24*544*DTR + 255)/256, 256, 0, stream>>>(dt_w, dtwT);
  k_init<<<ROWS, 64, 0, stream>>>(x0, xb, invr);
  for (int i=0;i<NL;i++){
    float lam_init = 0.8f - 0.6f*expf(-0.3f*(float)i);
    k_inproj<<<dim3(16,34), 256, 0, stream>>>(xb, invr, n1w + (size_t)i*DM,
        in_w + (size_t)i*2176*272, xz);
    k_xdt<<<512, 256, 0, stream>>>(xz,
        conv_w + (size_t)i*2*DI*4, conv_b + (size_t)i*2*DI,
        x_w + (size_t)i*2*81*DI, dtwT + (size_t)i*2*DTR*DI, dt_b + (size_t)i*2*DI,
        xcT, dtT, zT, Bm, Cm);
    k_scan<<<dim3(DI,NB,2), 128, 0, stream>>>(dtT, xcT, Bm, Cm,
        a_log + (size_t)i*2*DI*DS, dskip + (size_t)i*2*DI, zT, yoT);
    k_outproj<<<dim3(16,9,2), 128, 0, stream>>>(yoT, out_w + (size_t)i*2*DM*DI, y12);
    k_combine<<<ROWS, 256, 0, stream>>>(y12, lamq + (size_t)i*DM, n2w + (size_t)i*DM,
        xb, invr, lam_init, 1.f - lam_init);
  }
  k_head1<<<dim3(8,2), 256, 0, stream>>>(xb, xmp);
  k_head2<<<1, 256, 0, stream>>>(xmp, yin, mlpw, mlpb, pw, pb, outp);
}

// Round 5
// 1629.718 us; speedup vs baseline: 1.1186x; 1.1186x over previous
//
#include <hip/hip_runtime.h>
#include <math.h>

#define DM   272
#define DS   32
#define DI   544
#define DTR  17
#define SEQL 512
#define NB   2
#define ROWS 1024
#define DXZ  1088
#define NL   12

// workspace offsets (in floats)
#define OFF_X     0          // 1024*272
#define OFF_INVR  278528     // 1024
#define OFF_XZ    279552     // 4*512*1088 = 2228224
#define OFF_XCT   2507776    // 4*544*512  = 1114112  (channel-major)
#define OFF_DTT   3621888    // 4*544*512
#define OFF_ZT    4736000    // 4*544*512
#define OFF_BM    5850112    // 4*512*32 = 65536
#define OFF_CM    5915648    // 4*512*32
#define OFF_YOT   5981184    // 4*544*512  (channel-major)
#define OFF_Y12   7095296    // 2*1024*272 = 557056
#define OFF_XMP   7652352    // 16*272
#define OFF_DTWT  7656704    // 24*17*544  = 221952
// end: 7,878,656 floats = 31.5 MB

__device__ __forceinline__ float sigmoid_fast(float x){ return 1.f/(1.f+__expf(-x)); }
__device__ __forceinline__ float softplus_f(float x){ return (x > 20.f) ? x : log1pf(__expf(x)); }

__device__ __forceinline__ float block_reduce_256(float v, volatile float* sred, int tid){
#pragma unroll
  for (int m=32; m>=1; m>>=1) v += __shfl_xor(v, m);
  __syncthreads();
  if ((tid & 63) == 0) sred[tid>>6] = v;
  __syncthreads();
  return sred[0]+sred[1]+sred[2]+sred[3];
}

// ---------------------------------------------------------------- init
__global__ __launch_bounds__(64) void k_init(const float* __restrict__ x0,
                                             float* __restrict__ xb, float* __restrict__ invr){
  int r = blockIdx.x, tid = threadIdx.x;
  float ss = 0.f;
  for (int c=tid; c<DM; c+=64){ float v = x0[(size_t)r*DM+c]; xb[(size_t)r*DM+c]=v; ss += v*v; }
#pragma unroll
  for (int m=32;m>=1;m>>=1) ss += __shfl_xor(ss,m);
  if (tid==0) invr[r] = rsqrtf(ss*(1.f/DM)+1e-5f);
}

// ---------------------------------------------------------------- dt_proj weight transpose
// dtw [24][544][17] -> dtwT [24][17][544]
__global__ __launch_bounds__(256) void k_transpose(const float* __restrict__ dtw,
                                                   float* __restrict__ dtwT){
  int idx = blockIdx.x*256 + threadIdx.x;
  const int T2 = 24*544*DTR;
  if (idx < T2){
    int ld = idx / (544*DTR); int rem = idx - ld*(544*DTR);
    int d = rem / DTR; int r = rem - d*DTR;
    dtwT[(size_t)ld*DTR*544 + (size_t)r*544 + d] = dtw[idx];
  }
}

// ---------------------------------------------------------------- in_proj GEMM (rmsnorm fused)
__global__ __launch_bounds__(256) void k_inproj(
    const float* __restrict__ xb, const float* __restrict__ invr,
    const float* __restrict__ n1w, const float* __restrict__ inw,
    float* __restrict__ xz)
{
  __shared__ float As[16][76];
  __shared__ float Bs[16][76];
  const int tid = threadIdx.x;
  const int m0 = blockIdx.x << 6;
  const int nt = blockIdx.y;                    // 0..33
  const int dir = (nt >= 17) ? 1 : 0;
  const int n0l = (nt - dir*17) << 6;
  const float* wb = inw + (size_t)(dir*1088 + n0l)*272;
  const int tr = tid & 15, tc = tid >> 4;
  const int lr = tid >> 2, lk = (tid & 3) << 2;
  const float ivr = invr[m0 + lr];
  const float* xrow = xb + (size_t)(m0 + lr)*272;
  const float* wrow = wb + (size_t)lr*272;
  float acc[4][4];
#pragma unroll
  for (int i=0;i<4;i++)
#pragma unroll
    for (int j=0;j<4;j++) acc[i][j]=0.f;
  for (int k0=0;k0<272;k0+=16){
    float4 a4 = *(const float4*)(xrow + k0 + lk);
    float4 g4 = *(const float4*)(n1w + k0 + lk);
    float4 b4 = *(const float4*)(wrow + k0 + lk);
    As[lk+0][lr] = a4.x*ivr*g4.x;
    As[lk+1][lr] = a4.y*ivr*g4.y;
    As[lk+2][lr] = a4.z*ivr*g4.z;
    As[lk+3][lr] = a4.w*ivr*g4.w;
    Bs[lk+0][lr] = b4.x; Bs[lk+1][lr]=b4.y; Bs[lk+2][lr]=b4.z; Bs[lk+3][lr]=b4.w;
    __syncthreads();
#pragma unroll
    for (int kk=0;kk<16;kk++){
      float4 av = *(const float4*)(&As[kk][tr<<2]);
      float4 bv = *(const float4*)(&Bs[kk][tc<<2]);
      acc[0][0]+=av.x*bv.x; acc[0][1]+=av.x*bv.y; acc[0][2]+=av.x*bv.z; acc[0][3]+=av.x*bv.w;
      acc[1][0]+=av.y*bv.x; acc[1][1]+=av.y*bv.y; acc[1][2]+=av.y*bv.z; acc[1][3]+=av.y*bv.w;
      acc[2][0]+=av.z*bv.x; acc[2][1]+=av.z*bv.y; acc[2][2]+=av.z*bv.z; acc[2][3]+=av.z*bv.w;
      acc[3][0]+=av.w*bv.x; acc[3][1]+=av.w*bv.y; acc[3][2]+=av.w*bv.z; acc[3][3]+=av.w*bv.w;
    }
    __syncthreads();
  }
#pragma unroll
  for (int i=0;i<4;i++){
    int r = m0 + (tr<<2) + i;
    int b = r >> 9, t = r & 511;
    int ts = dir ? (511 - t) : t;
    float4 v = make_float4(acc[i][0],acc[i][1],acc[i][2],acc[i][3]);
    *(float4*)(xz + (size_t)((dir*NB + b)*SEQL + ts)*DXZ + n0l + (tc<<2)) = v;
  }
}

// ---------------------------------------------------------------- conv4+silu + x_proj + dt_proj
// 8-row tiles, 512 threads, grid 256; x_proj e-major with 2 e-cols/thread
__global__ __launch_bounds__(512) void k_xdt(
  const float* __restrict__ xz, const float* __restrict__ cwl, const float* __restrict__ cbl,
  const float* __restrict__ xwl, const float* __restrict__ dtwTl, const float* __restrict__ dtbl,
  float* __restrict__ xcT, float* __restrict__ dtT, float* __restrict__ zT,
  float* __restrict__ Bmg, float* __restrict__ Cmg)
{
  __shared__ float xcs[8][548];
  __shared__ float part[8][8][82];   // [ks][row][e]
  __shared__ float dts[8][DTR];
  const int tid = threadIdx.x;
  const int blk = blockIdx.x;        // 0..255
  const int seg = blk >> 6;          // dir*2 + b
  const int dir = seg >> 1;
  const int t0 = (blk & 63) << 3;
  const float* xzb  = xz + (size_t)seg*SEQL*DXZ;
  const float* cw   = cwl + dir*DI*4;
  const float* cb   = cbl + dir*DI;
  const float* xw   = xwl + (size_t)dir*81*DI;   // [e][544] rows
  const float* dtwT = dtwTl + (size_t)dir*DTR*DI;
  const float* dtb  = dtbl + dir*DI;
  const size_t chb = (size_t)seg*DI;  // channel-row base

  // phase 1: conv4 + silu (+ z extract), 32 B channel-major row stores
  for (int j = tid; j < DI; j += 512){
    float4 w4 = *(const float4*)(cw + j*4);
    float bj = cb[j];
    float xv[11];
#pragma unroll
    for (int q=0; q<11; q++){
      int t = t0 + q - 3;
      xv[q] = (t >= 0) ? xzb[(size_t)t*DXZ + j] : 0.f;
    }
    float xo[8], zo[8];
#pragma unroll
    for (int rr=0; rr<8; rr++){
      float acc = bj + w4.x*xv[rr] + w4.y*xv[rr+1] + w4.z*xv[rr+2] + w4.w*xv[rr+3];
      float v = acc * sigmoid_fast(acc);
      xcs[rr][j] = v; xo[rr] = v;
      zo[rr] = xzb[(size_t)(t0+rr)*DXZ + 544 + j];
    }
    float* xr = xcT + (chb + j)*SEQL + t0;
    *(float4*)(xr)   = make_float4(xo[0],xo[1],xo[2],xo[3]);
    *(float4*)(xr+4) = make_float4(xo[4],xo[5],xo[6],xo[7]);
    float* zr = zT + (chb + j)*SEQL + t0;
    *(float4*)(zr)   = make_float4(zo[0],zo[1],zo[2],zo[3]);
    *(float4*)(zr+4) = make_float4(zo[4],zo[5],zo[6],zo[7]);
  }
  __syncthreads();

  // phase 2: x_proj — thread owns (e-pair, k-slice of 68); weights reused over 8 rows
  if (tid < 328){
    const int i = tid >> 3, ks = tid & 7;   // i: 0..40
    const int e0 = 2*i;
    const int e1r = (e0+1 < 81) ? (e0+1) : 80;   // clamped read row (i=40 dup)
    const int kb = ks*68;
    const float* w0 = xw + (size_t)e0*DI + kb;
    const float* w1 = xw + (size_t)e1r*DI + kb;
    float acc0[8], acc1[8];
#pragma unroll
    for (int rr=0; rr<8; rr++){ acc0[rr]=0.f; acc1[rr]=0.f; }
    for (int k=0; k<68; k+=4){
      float4 wa = *(const float4*)(w0 + k);
      float4 wb = *(const float4*)(w1 + k);
#pragma unroll
      for (int rr=0; rr<8; rr++){
        float4 x4 = *(const float4*)(&xcs[rr][kb + k]);
        acc0[rr] = fmaf(wa.x,x4.x, fmaf(wa.y,x4.y, fmaf(wa.z,x4.z, fmaf(wa.w,x4.w, acc0[rr]))));
        acc1[rr] = fmaf(wb.x,x4.x, fmaf(wb.y,x4.y, fmaf(wb.z,x4.z, fmaf(wb.w,x4.w, acc1[rr]))));
      }
    }
#pragma unroll
    for (int rr=0; rr<8; rr++){
      part[ks][rr][e0]   = acc0[rr];
      part[ks][rr][e0+1] = acc1[rr];   // e0+1==81 lands in pad, unused
    }
  }
  __syncthreads();

  // reduce 8 k-slices, route to dts / Bm / Cm
  for (int idx=tid; idx<648; idx+=512){
    int ta = idx / 81, e = idx - ta*81;
    float s = 0.f;
#pragma unroll
    for (int ks=0; ks<8; ks++) s += part[ks][ta][e];
    size_t row = (size_t)seg*SEQL + t0 + ta;
    if (e < DTR)      dts[ta][e] = s;
    else if (e < 49)  Bmg[row*DS + (e-DTR)] = s;
    else              Cmg[row*DS + (e-49)] = s;
  }
  __syncthreads();

  // phase 3: dt_proj + softplus, channel-major row stores
  {
    const int c1 = tid;
    const bool h2 = tid < 32; const int c2 = 512 + tid;
    float w1[DTR], w2[DTR];
#pragma unroll
    for (int q=0; q<DTR; q++){
      w1[q] = dtwT[q*DI + c1];
      w2[q] = h2 ? dtwT[q*DI + c2] : 0.f;
    }
    float b1 = dtb[c1], b2 = h2 ? dtb[c2] : 0.f;
    float o1[8], o2[8];
#pragma unroll
    for (int rr=0; rr<8; rr++){
      float a1=b1, a2=b2;
#pragma unroll
      for (int q=0; q<DTR; q++){
        float dv = dts[rr][q];
        a1 = fmaf(w1[q],dv,a1); a2 = fmaf(w2[q],dv,a2);
      }
      o1[rr]=softplus_f(a1); o2[rr]=softplus_f(a2);
    }
    float* r1 = dtT + (chb + c1)*SEQL + t0;
    *(float4*)(r1)   = make_float4(o1[0],o1[1],o1[2],o1[3]);
    *(float4*)(r1+4) = make_float4(o1[4],o1[5],o1[6],o1[7]);
    if (h2){
      float* r2 = dtT + (chb + c2)*SEQL + t0;
      *(float4*)(r2)   = make_float4(o2[0],o2[1],o2[2],o2[3]);
      *(float4*)(r2+4) = make_float4(o2[4],o2[5],o2[6],o2[7]);
    }
  }
}

// ---------------------------------------------------------------- chunked selective scan + gate
__global__ __launch_bounds__(128) void k_scan(
  const float* __restrict__ dtT, const float* __restrict__ xcT,
  const float* __restrict__ Bmg, const float* __restrict__ Cmg,
  const float* __restrict__ alogl, const float* __restrict__ dskl,
  const float* __restrict__ zT, float* __restrict__ yoT)
{
  __shared__ float hl[16][33], pl[16][33], Hi[16][33];
  const int d = blockIdx.x, b = blockIdx.y, dir = blockIdx.z;
  const int seg = dir*NB + b;
  const int tid = threadIdx.x;
  const int c = tid >> 3, sg = tid & 7, s0 = sg << 2;
  float A0,A1,A2,A3;
  {
    const float* al = alogl + (size_t)(dir*DI + d)*DS + s0;
    A0 = -expf(al[0]); A1 = -expf(al[1]); A2 = -expf(al[2]); A3 = -expf(al[3]);
  }
  const size_t cr = ((size_t)seg*DI + d)*SEQL;
  const float* dtr = dtT + cr;
  const float* xcr = xcT + cr;
  const float* zr  = zT  + cr;
  float* yor = yoT + cr;
  const float* Bp = Bmg + (size_t)seg*SEQL*DS + s0;
  const float* Cp = Cmg + (size_t)seg*SEQL*DS + s0;
  float h0=0,h1=0,h2=0,h3=0,p0=1,p1=1,p2=1,p3=1;
  const int tb = c << 5;
  for (int tq=0; tq<8; tq++){
    const int t4 = tb + (tq<<2);
    float4 dt4 = *(const float4*)(dtr + t4);
    const float* dtp4 = (const float*)&dt4;
    float4 xc4 = *(const float4*)(xcr + t4);
    const float* xcp4 = (const float*)&xc4;
#pragma unroll
    for (int u=0; u<4; u++){
      float ldt = dtp4[u], lxc = xcp4[u];
      float4 B4 = *(const float4*)(Bp + (size_t)(t4+u)*DS);
      float uu = ldt*lxc;
      float e;
      e = __expf(ldt*A0); h0 = fmaf(e,h0,uu*B4.x); p0*=e;
      e = __expf(ldt*A1); h1 = fmaf(e,h1,uu*B4.y); p1*=e;
      e = __expf(ldt*A2); h2 = fmaf(e,h2,uu*B4.z); p2*=e;
      e = __expf(ldt*A3); h3 = fmaf(e,h3,uu*B4.w); p3*=e;
    }
  }
  hl[c][s0]=h0; hl[c][s0+1]=h1; hl[c][s0+2]=h2; hl[c][s0+3]=h3;
  pl[c][s0]=p0; pl[c][s0+1]=p1; pl[c][s0+2]=p2; pl[c][s0+3]=p3;
  __syncthreads();
  if (tid < 32){
    float H = 0.f;
    Hi[0][tid] = 0.f;
    for (int cc=1; cc<16; cc++){
      H = fmaf(pl[cc-1][tid], H, hl[cc-1][tid]);
      Hi[cc][tid] = H;
    }
  }
  __syncthreads();
  h0=Hi[c][s0]; h1=Hi[c][s0+1]; h2=Hi[c][s0+2]; h3=Hi[c][s0+3];
  const float dsk = dskl[dir*DI + d];
  for (int tq=0; tq<8; tq++){
    const int t4 = tb + (tq<<2);
    float4 dt4 = *(const float4*)(dtr + t4);
    const float* dtp4 = (const float*)&dt4;
    float4 xc4 = *(const float4*)(xcr + t4);
    const float* xcp4 = (const float*)&xc4;
    float4 z4 = *(const float4*)(zr + t4);
    const float* zp4 = (const float*)&z4;
    float yv[4];
#pragma unroll
    for (int u=0; u<4; u++){
      float ldt = dtp4[u], lxc = xcp4[u];
      float4 B4 = *(const float4*)(Bp + (size_t)(t4+u)*DS);
      float4 C4 = *(const float4*)(Cp + (size_t)(t4+u)*DS);
      float uu = ldt*lxc;
      float e;
      e = __expf(ldt*A0); h0 = fmaf(e,h0,uu*B4.x);
      e = __expf(ldt*A1); h1 = fmaf(e,h1,uu*B4.y);
      e = __expf(ldt*A2); h2 = fmaf(e,h2,uu*B4.z);
      e = __expf(ldt*A3); h3 = fmaf(e,h3,uu*B4.w);
      float y = h0*C4.x + h1*C4.y + h2*C4.z + h3*C4.w;
      y += __shfl_xor(y,1); y += __shfl_xor(y,2); y += __shfl_xor(y,4);
      float z = zp4[u];
      yv[u] = fmaf(dsk, lxc, y) * (z * sigmoid_fast(z));
    }
    if (sg==0) *(float4*)(yor + t4) = make_float4(yv[0],yv[1],yv[2],yv[3]);
  }
}

// ---------------------------------------------------------------- out_proj GEMM (A = yoT channel-major)
__global__ __launch_bounds__(128) void k_outproj(
    const float* __restrict__ yoT, const float* __restrict__ ow, float* __restrict__ y12)
{
  __shared__ float As[16][68];
  __shared__ float Bs[16][40];
  const int tid = threadIdx.x;
  const int m0 = blockIdx.x << 6;
  const int n0 = blockIdx.y << 5;
  const int dir = blockIdx.z;
  const int bseg = m0 >> 9;
  const int t0 = m0 & 511;
  const float* At = yoT + (size_t)(dir*NB + bseg)*DI*SEQL;
  const float* W = ow + (size_t)dir*DM*DI;
  const int smi = (tid & 15) << 2;
  const int skk = tid >> 4;
  const int lrb = tid >> 2, lkb = (tid & 3) << 2;
  const int tr = tid & 15, tc = tid >> 4;
  const int nb = n0 + lrb;
  const bool bvalid = nb < DM;
  const float* wrow = W + (size_t)(bvalid ? nb : 0)*DI;
  float acc[4][4];
#pragma unroll
  for (int i=0;i<4;i++)
#pragma unroll
    for (int j=0;j<4;j++) acc[i][j]=0.f;
  for (int k0=0;k0<544;k0+=16){
    float4 a0 = *(const float4*)(At + (size_t)(k0+skk)*SEQL + t0 + smi);
    float4 a1 = *(const float4*)(At + (size_t)(k0+skk+8)*SEQL + t0 + smi);
    *(float4*)(&As[skk][smi])   = a0;
    *(float4*)(&As[skk+8][smi]) = a1;
    float4 b4 = bvalid ? *(const float4*)(wrow + k0 + lkb) : make_float4(0.f,0.f,0.f,0.f);
    Bs[lkb+0][lrb]=b4.x; Bs[lkb+1][lrb]=b4.y; Bs[lkb+2][lrb]=b4.z; Bs[lkb+3][lrb]=b4.w;
    __syncthreads();
#pragma unroll
    for (int kk=0;kk<16;kk++){
      float4 av = *(const float4*)(&As[kk][tr<<2]);
      float4 bv = *(const float4*)(&Bs[kk][tc<<2]);
      acc[0][0]+=av.x*bv.x; acc[0][1]+=av.x*bv.y; acc[0][2]+=av.x*bv.z; acc[0][3]+=av.x*bv.w;
      acc[1][0]+=av.y*bv.x; acc[1][1]+=av.y*bv.y; acc[1][2]+=av.y*bv.z; acc[1][3]+=av.y*bv.w;
      acc[2][0]+=av.z*bv.x; acc[2][1]+=av.z*bv.y; acc[2][2]+=av.z*bv.z; acc[2][3]+=av.z*bv.w;
      acc[3][0]+=av.w*bv.x; acc[3][1]+=av.w*bv.y; acc[3][2]+=av.w*bv.z; acc[3][3]+=av.w*bv.w;
    }
    __syncthreads();
  }
  int col = n0 + (tc<<2);
  if (col < DM){
#pragma unroll
    for (int i=0;i<4;i++){
      int r = m0 + (tr<<2) + i;
      int b = r >> 9, t = r & 511;
      int ts = dir ? (511 - t) : t;
      float4 v = make_float4(acc[i][0],acc[i][1],acc[i][2],acc[i][3]);
      *(float4*)(y12 + (size_t)dir*ROWS*DM + (size_t)(b*SEQL+ts)*DM + col) = v;
    }
  }
}

// ---------------------------------------------------------------- combine
__global__ __launch_bounds__(256) void k_combine(
  const float* __restrict__ y12, const float* __restrict__ lamq,
  const float* __restrict__ n2w, float* __restrict__ xb,
  float* __restrict__ invr, float lam_init, float omli)
{
  __shared__ float sred[4];
  const int tid = threadIdx.x;
  const int r = blockIdx.x;
  const float* y1 = y12 + (size_t)r*DM;
  const float* y2 = y12 + (size_t)ROWS*DM + (size_t)r*DM;
  float lp = lamq[tid];
  if (tid < 16) lp += lamq[tid+256];
  float lsum = block_reduce_256(lp, sred, tid);
  float lam = sigmoid_fast(lsum) + lam_init;
  float a0 = y1[tid] - lam*y2[tid];
  float a1 = 0.f;
  if (tid<16) a1 = y1[tid+256] - lam*y2[tid+256];
  float ss = block_reduce_256(a0*a0 + a1*a1, sred, tid);
  float rms = rsqrtf(ss*(1.f/DM) + 1e-5f);
  float xo0 = xb[(size_t)r*DM + tid] + a0*rms*n2w[tid]*omli;
  float xo1 = 0.f;
  if (tid<16) xo1 = xb[(size_t)r*DM + tid+256] + a1*rms*n2w[tid+256]*omli;
  xb[(size_t)r*DM+tid] = xo0;
  if (tid<16) xb[(size_t)r*DM+tid+256] = xo1;
  float ss2 = block_reduce_256(xo0*xo0 + xo1*xo1, sred, tid);
  if (tid==0) invr[r] = rsqrtf(ss2*(1.f/DM) + 1e-5f);
}

// ---------------------------------------------------------------- head
__global__ __launch_bounds__(256) void k_head1(const float* __restrict__ xb, float* __restrict__ xmp){
  int ch = blockIdx.x, b = blockIdx.y, tid = threadIdx.x;
  int t0 = ch*64;
  float s0=0.f, s1=0.f;
  for (int t=t0; t<t0+64; t++){
    const float* row = xb + (size_t)(b*SEQL+t)*DM;
    s0 += row[tid];
    if (tid<16) s1 += row[tid+256];
  }
  xmp[(size_t)(b*8+ch)*DM + tid] = s0;
  if (tid<16) xmp[(size_t)(b*8+ch)*DM + tid+256] = s1;
}

__global__ __launch_bounds__(256) void k_head2(
  const float* __restrict__ xmp, const float* __restrict__ yin,
  const float* __restrict__ mlpw, const float* __restrict__ mlpb,
  const float* __restrict__ pw, const float* __restrict__ pb,
  float* __restrict__ out)
{
  __shared__ float xm[2][DM];
  __shared__ float x2s[2][DM];
  __shared__ float sred[4];
  int tid = threadIdx.x;
  for (int idx=tid; idx<2*DM; idx+=256){
    int b = idx / DM, c = idx - b*DM;
    float s=0.f;
    for (int ch=0; ch<8; ch++) s += xmp[(size_t)(b*8+ch)*DM + c];
    xm[b][c] = s * (1.f/SEQL);
  }
  __syncthreads();
  for (int idx=tid; idx<2*DM; idx+=256){
    int b = idx / DM, c = idx - b*DM;
    float acc = mlpb[c];
    const float* wr = mlpw + (size_t)c*DM;
    for (int k=0;k<DM;k++) acc += wr[k]*xm[b][k];
    float v = fmaxf(acc, 0.f);
    x2s[b][c] = v;
    out[2 + b*DM + c] = v;
  }
  __syncthreads();
  for (int b=0;b<2;b++){
    float p = x2s[b][tid]*pw[tid];
    if (tid<16) p += x2s[b][tid+256]*pw[tid+256];
    float tot = block_reduce_256(p, sred, tid);
    if (tid==0) out[b] = tot + yin[b]*pw[DM] + pb[0];
  }
}

// ----------------------------------------------------------------
extern "C" void kernel_launch(void* const* d_in, const int* in_sizes, int n_in,
                              void* d_out, int out_size, void* d_ws, size_t ws_size,
                              hipStream_t stream)
{
  const float* x0     = (const float*)d_in[0];
  const float* yin    = (const float*)d_in[1];
  const float* in_w   = (const float*)d_in[2];
  const float* conv_w = (const float*)d_in[3];
  const float* conv_b = (const float*)d_in[4];
  const float* x_w    = (const float*)d_in[5];
  const float* dt_w   = (const float*)d_in[6];
  const float* dt_b   = (const float*)d_in[7];
  const float* a_log  = (const float*)d_in[8];
  const float* dskip  = (const float*)d_in[9];
  const float* out_w  = (const float*)d_in[10];
  const float* lamq   = (const float*)d_in[11];
  const float* n1w    = (const float*)d_in[12];
  const float* n2w    = (const float*)d_in[13];
  const float* mlpw   = (const float*)d_in[14];
  const float* mlpb   = (const float*)d_in[15];
  const float* pw     = (const float*)d_in[16];
  const float* pb     = (const float*)d_in[17];

  float* ws  = (float*)d_ws;
  float* xb  = ws + OFF_X;
  float* invr= ws + OFF_INVR;
  float* xz  = ws + OFF_XZ;
  float* xcT = ws + OFF_XCT;
  float* dtT = ws + OFF_DTT;
  float* zT  = ws + OFF_ZT;
  float* Bm  = ws + OFF_BM;
  float* Cm  = ws + OFF_CM;
  float* yoT = ws + OFF_YOT;
  float* y12 = ws + OFF_Y12;
  float* xmp = ws + OFF_XMP;
  float* dtwT= ws + OFF_DTWT;
  float* outp = (float*)d_out;

  k_transpose<<<(24*544*DTR + 255)/256, 256, 0, stream>>>(dt_w, dtwT);
  k_init<<<ROWS, 64, 0, stream>>>(x0, xb, invr);
  for (int i=0;i<NL;i++){
    float lam_init = 0.8f - 0.6f*expf(-0.3f*(float)i);
    k_inproj<<<dim3(16,34), 256, 0, stream>>>(xb, invr, n1w + (size_t)i*DM,
        in_w + (size_t)i*2176*272, xz);
    k_xdt<<<256, 512, 0, stream>>>(xz,
        conv_w + (size_t)i*2*DI*4, conv_b + (size_t)i*2*DI,
        x_w + (size_t)i*2*81*DI, dtwT + (size_t)i*2*DTR*DI, dt_b + (size_t)i*2*DI,
        xcT, dtT, zT, Bm, Cm);
    k_scan<<<dim3(DI,NB,2), 128, 0, stream>>>(dtT, xcT, Bm, Cm,
        a_log + (size_t)i*2*DI*DS, dskip + (size_t)i*2*DI, zT, yoT);
    k_outproj<<<dim3(16,9,2), 128, 0, stream>>>(yoT, out_w + (size_t)i*2*DM*DI, y12);
    k_combine<<<ROWS, 256, 0, stream>>>(y12, lamq + (size_t)i*DM, n2w + (size_t)i*DM,
        xb, invr, lam_init, 1.f - lam_init);
  }
  k_head1<<<dim3(8,2), 256, 0, stream>>>(xb, xmp);
  k_head2<<<1, 256, 0, stream>>>(xmp, yin, mlpw, mlpb, pw, pb, outp);
}

// Round 6
// 1389.849 us; speedup vs baseline: 1.3117x; 1.1726x over previous
//
#include <hip/hip_runtime.h>
#include <math.h>

#define DM   272
#define DS   32
#define DI   544
#define DTR  17
#define SEQL 512
#define NB   2
#define ROWS 1024
#define DXZ  1088
#define NL   12
#define KP   288            // padded K for in_proj (272->288)

typedef unsigned short ushort_t;
typedef __attribute__((ext_vector_type(8))) short bx8;   // 8 bf16 (4 VGPRs)
typedef __attribute__((ext_vector_type(4))) float fx4;   // MFMA accumulator

// workspace offsets (in floats)
#define OFF_X     0          // 1024*272
#define OFF_XZ    279552     // 4*512*1088 = 2228224
#define OFF_XCT   2507776    // 4*544*512  (channel-major)
#define OFF_DTT   3621888
#define OFF_ZT    4736000
#define OFF_BM    5850112    // 4*512*32
#define OFF_CM    5915648
#define OFF_YOT   5981184    // 4*544*512  (channel-major)
#define OFF_Y12   7095296    // 2*1024*272
#define OFF_XMP   7652352    // 16*272
#define OFF_DTWT  7656704    // 24*17*544
#define OFF_XNH   7878656    // 1024*288 bf16 = 147456 floats
#define OFF_XNL   8026112
#define OFF_YTMH  8173568    // 4*512*544 bf16 = 557056 floats
#define OFF_YTML  8730624
#define OFF_WINH  9287680    // 12*2176*288 bf16 = 3760128 floats
#define OFF_WINL  13047808
#define OFF_WOUTH 16807936   // 12*544*544 bf16 = 1775616 floats
#define OFF_WOUTL 18583552
// end: 20,359,168 floats = 81.4 MB

#define NINW  (12*2176*KP)
#define NOUTW (12*544*544)

__device__ __forceinline__ float sigmoid_fast(float x){ return 1.f/(1.f+__expf(-x)); }
__device__ __forceinline__ float softplus_f(float x){ return (x > 20.f) ? x : log1pf(__expf(x)); }

__device__ __forceinline__ void bf16split(float x, ushort_t& h, ushort_t& l){
  unsigned uh = __float_as_uint(x) & 0xffff0000u;
  h = (ushort_t)(uh >> 16);
  float r = x - __uint_as_float(uh);           // exact
  l = (ushort_t)(__float_as_uint(r) >> 16);
}

__device__ __forceinline__ float block_reduce_256(float v, volatile float* sred, int tid){
#pragma unroll
  for (int m=32; m>=1; m>>=1) v += __shfl_xor(v, m);
  __syncthreads();
  if ((tid & 63) == 0) sred[tid>>6] = v;
  __syncthreads();
  return sred[0]+sred[1]+sred[2]+sred[3];
}

// ---------------------------------------------------------------- weight conversion (once per call)
__global__ __launch_bounds__(256) void k_convw(const float* __restrict__ inw,
    const float* __restrict__ outw,
    ushort_t* __restrict__ winh, ushort_t* __restrict__ winl,
    ushort_t* __restrict__ wouth, ushort_t* __restrict__ woutl)
{
  int idx = blockIdx.x*256 + threadIdx.x;
  if (idx < NINW){
    int k = idx % KP; int row = idx / KP;
    float v = (k < DM) ? inw[(size_t)row*DM + k] : 0.f;
    ushort_t h,l; bf16split(v,h,l);
    winh[idx]=h; winl[idx]=l;
  } else if (idx < NINW + NOUTW){
    int j = idx - NINW;
    float v = outw[j];
    ushort_t h,l; bf16split(v,h,l);
    wouth[j]=h; woutl[j]=l;
  }
}

// ---------------------------------------------------------------- dt_proj weight transpose
__global__ __launch_bounds__(256) void k_transpose(const float* __restrict__ dtw,
                                                   float* __restrict__ dtwT){
  int idx = blockIdx.x*256 + threadIdx.x;
  const int T2 = 24*544*DTR;
  if (idx < T2){
    int ld = idx / (544*DTR); int rem = idx - ld*(544*DTR);
    int d = rem / DTR; int r = rem - d*DTR;
    dtwT[(size_t)ld*DTR*544 + (size_t)r*544 + d] = dtw[idx];
  }
}

// ---------------------------------------------------------------- init: copy x, rmsnorm -> xn bf16 hi/lo
__global__ __launch_bounds__(64) void k_init(const float* __restrict__ x0,
                                             const float* __restrict__ n1w0,
                                             float* __restrict__ xb,
                                             ushort_t* __restrict__ xnh, ushort_t* __restrict__ xnl){
  int r = blockIdx.x, tid = threadIdx.x;
  float vv[5]; float ss = 0.f;
#pragma unroll
  for (int i=0;i<5;i++){
    int c = tid + i*64; float v = 0.f;
    if (c < DM){ v = x0[(size_t)r*DM+c]; xb[(size_t)r*DM+c]=v; }
    vv[i]=v; ss += v*v;
  }
#pragma unroll
  for (int m=32;m>=1;m>>=1) ss += __shfl_xor(ss,m);
  float ivr = rsqrtf(ss*(1.f/DM)+1e-5f);
#pragma unroll
  for (int i=0;i<5;i++){
    int c = tid + i*64;
    if (c < DM){
      ushort_t h,l; bf16split(vv[i]*ivr*n1w0[c],h,l);
      xnh[(size_t)r*KP+c]=h; xnl[(size_t)r*KP+c]=l;
    }
  }
  if (tid < 16){ xnh[(size_t)r*KP+DM+tid]=0; xnl[(size_t)r*KP+DM+tid]=0; }
}

// ---------------------------------------------------------------- in_proj: split-bf16 MFMA GEMM
// C[1024 x 2176] = xn @ W^T ; dir1 rows stored time-flipped into xz
__global__ __launch_bounds__(256) void k_gin(
  const ushort_t* __restrict__ xnh, const ushort_t* __restrict__ xnl,
  const ushort_t* __restrict__ wh,  const ushort_t* __restrict__ wl,
  float* __restrict__ xz)
{
  const int tid = threadIdx.x;
  const int wv = tid >> 6, lane = tid & 63;
  const int m16 = lane & 15, quad = lane >> 4;
  const int q8 = quad << 3;
  const int m0 = blockIdx.x << 6;
  const int nt = blockIdx.y;                  // 0..33
  const int dir = (nt >= 17) ? 1 : 0;
  const int n0l = (nt - dir*17) << 6;
  const int ncol = n0l + (wv<<4) + m16;       // 0..1087 within dir
  const ushort_t* bhp = wh + (size_t)(dir*1088 + ncol)*KP + q8;
  const ushort_t* blp = wl + (size_t)(dir*1088 + ncol)*KP + q8;
  const ushort_t* ahp = xnh + (size_t)(m0 + m16)*KP + q8;
  const ushort_t* alp = xnl + (size_t)(m0 + m16)*KP + q8;
  fx4 acc[4];
#pragma unroll
  for (int mt=0;mt<4;mt++) acc[mt] = (fx4){0.f,0.f,0.f,0.f};
  for (int k0=0;k0<KP;k0+=32){
    bx8 bh = *(const bx8*)(bhp + k0);
    bx8 bl = *(const bx8*)(blp + k0);
#pragma unroll
    for (int mt=0;mt<4;mt++){
      bx8 ah = *(const bx8*)(ahp + (size_t)mt*16*KP + k0);
      bx8 al = *(const bx8*)(alp + (size_t)mt*16*KP + k0);
      acc[mt] = __builtin_amdgcn_mfma_f32_16x16x32_bf16(ah, bh, acc[mt], 0,0,0);
      acc[mt] = __builtin_amdgcn_mfma_f32_16x16x32_bf16(al, bh, acc[mt], 0,0,0);
      acc[mt] = __builtin_amdgcn_mfma_f32_16x16x32_bf16(ah, bl, acc[mt], 0,0,0);
    }
  }
#pragma unroll
  for (int mt=0;mt<4;mt++){
#pragma unroll
    for (int r=0;r<4;r++){
      int rg = m0 + mt*16 + quad*4 + r;
      int b = rg >> 9, t = rg & 511;
      int ts = dir ? (511 - t) : t;
      xz[((size_t)((dir*NB + b)*SEQL + ts))*DXZ + ncol] = acc[mt][r];
    }
  }
}

// ---------------------------------------------------------------- conv4+silu + x_proj + dt_proj
__global__ __launch_bounds__(512) void k_xdt(
  const float* __restrict__ xz, const float* __restrict__ cwl, const float* __restrict__ cbl,
  const float* __restrict__ xwl, const float* __restrict__ dtwTl, const float* __restrict__ dtbl,
  float* __restrict__ xcT, float* __restrict__ dtT, float* __restrict__ zT,
  float* __restrict__ Bmg, float* __restrict__ Cmg)
{
  __shared__ float xcs[8][548];
  __shared__ float part[8][8][82];
  __shared__ float dts[8][DTR];
  const int tid = threadIdx.x;
  const int blk = blockIdx.x;
  const int seg = blk >> 6;
  const int dir = seg >> 1;
  const int t0 = (blk & 63) << 3;
  const float* xzb  = xz + (size_t)seg*SEQL*DXZ;
  const float* cw   = cwl + dir*DI*4;
  const float* cb   = cbl + dir*DI;
  const float* xw   = xwl + (size_t)dir*81*DI;
  const float* dtwT = dtwTl + (size_t)dir*DTR*DI;
  const float* dtb  = dtbl + dir*DI;
  const size_t chb = (size_t)seg*DI;

  for (int j = tid; j < DI; j += 512){
    float4 w4 = *(const float4*)(cw + j*4);
    float bj = cb[j];
    float xv[11];
#pragma unroll
    for (int q=0; q<11; q++){
      int t = t0 + q - 3;
      xv[q] = (t >= 0) ? xzb[(size_t)t*DXZ + j] : 0.f;
    }
    float xo[8], zo[8];
#pragma unroll
    for (int rr=0; rr<8; rr++){
      float acc = bj + w4.x*xv[rr] + w4.y*xv[rr+1] + w4.z*xv[rr+2] + w4.w*xv[rr+3];
      float v = acc * sigmoid_fast(acc);
      xcs[rr][j] = v; xo[rr] = v;
      zo[rr] = xzb[(size_t)(t0+rr)*DXZ + 544 + j];
    }
    float* xr = xcT + (chb + j)*SEQL + t0;
    *(float4*)(xr)   = make_float4(xo[0],xo[1],xo[2],xo[3]);
    *(float4*)(xr+4) = make_float4(xo[4],xo[5],xo[6],xo[7]);
    float* zr = zT + (chb + j)*SEQL + t0;
    *(float4*)(zr)   = make_float4(zo[0],zo[1],zo[2],zo[3]);
    *(float4*)(zr+4) = make_float4(zo[4],zo[5],zo[6],zo[7]);
  }
  __syncthreads();

  if (tid < 328){
    const int i = tid >> 3, ks = tid & 7;
    const int e0 = 2*i;
    const int e1r = (e0+1 < 81) ? (e0+1) : 80;
    const int kb = ks*68;
    const float* w0 = xw + (size_t)e0*DI + kb;
    const float* w1 = xw + (size_t)e1r*DI + kb;
    float acc0[8], acc1[8];
#pragma unroll
    for (int rr=0; rr<8; rr++){ acc0[rr]=0.f; acc1[rr]=0.f; }
    for (int k=0; k<68; k+=4){
      float4 wa = *(const float4*)(w0 + k);
      float4 wb = *(const float4*)(w1 + k);
#pragma unroll
      for (int rr=0; rr<8; rr++){
        float4 x4 = *(const float4*)(&xcs[rr][kb + k]);
        acc0[rr] = fmaf(wa.x,x4.x, fmaf(wa.y,x4.y, fmaf(wa.z,x4.z, fmaf(wa.w,x4.w, acc0[rr]))));
        acc1[rr] = fmaf(wb.x,x4.x, fmaf(wb.y,x4.y, fmaf(wb.z,x4.z, fmaf(wb.w,x4.w, acc1[rr]))));
      }
    }
#pragma unroll
    for (int rr=0; rr<8; rr++){
      part[ks][rr][e0]   = acc0[rr];
      part[ks][rr][e0+1] = acc1[rr];
    }
  }
  __syncthreads();

  for (int idx=tid; idx<648; idx+=512){
    int ta = idx / 81, e = idx - ta*81;
    float s = 0.f;
#pragma unroll
    for (int ks=0; ks<8; ks++) s += part[ks][ta][e];
    size_t row = (size_t)seg*SEQL + t0 + ta;
    if (e < DTR)      dts[ta][e] = s;
    else if (e < 49)  Bmg[row*DS + (e-DTR)] = s;
    else              Cmg[row*DS + (e-49)] = s;
  }
  __syncthreads();

  {
    const int c1 = tid;
    const bool h2 = tid < 32; const int c2 = 512 + tid;
    float w1[DTR], w2[DTR];
#pragma unroll
    for (int q=0; q<DTR; q++){
      w1[q] = dtwT[q*DI + c1];
      w2[q] = h2 ? dtwT[q*DI + c2] : 0.f;
    }
    float b1 = dtb[c1], b2 = h2 ? dtb[c2] : 0.f;
    float o1[8], o2[8];
#pragma unroll
    for (int rr=0; rr<8; rr++){
      float a1=b1, a2=b2;
#pragma unroll
      for (int q=0; q<DTR; q++){
        float dv = dts[rr][q];
        a1 = fmaf(w1[q],dv,a1); a2 = fmaf(w2[q],dv,a2);
      }
      o1[rr]=softplus_f(a1); o2[rr]=softplus_f(a2);
    }
    float* r1 = dtT + (chb + c1)*SEQL + t0;
    *(float4*)(r1)   = make_float4(o1[0],o1[1],o1[2],o1[3]);
    *(float4*)(r1+4) = make_float4(o1[4],o1[5],o1[6],o1[7]);
    if (h2){
      float* r2 = dtT + (chb + c2)*SEQL + t0;
      *(float4*)(r2)   = make_float4(o2[0],o2[1],o2[2],o2[3]);
      *(float4*)(r2+4) = make_float4(o2[4],o2[5],o2[6],o2[7]);
    }
  }
}

// ---------------------------------------------------------------- chunked selective scan + gate
__global__ __launch_bounds__(128) void k_scan(
  const float* __restrict__ dtT, const float* __restrict__ xcT,
  const float* __restrict__ Bmg, const float* __restrict__ Cmg,
  const float* __restrict__ alogl, const float* __restrict__ dskl,
  const float* __restrict__ zT, float* __restrict__ yoT)
{
  __shared__ float hl[16][33], pl[16][33], Hi[16][33];
  const int d = blockIdx.x, b = blockIdx.y, dir = blockIdx.z;
  const int seg = dir*NB + b;
  const int tid = threadIdx.x;
  const int c = tid >> 3, sg = tid & 7, s0 = sg << 2;
  float A0,A1,A2,A3;
  {
    const float* al = alogl + (size_t)(dir*DI + d)*DS + s0;
    A0 = -expf(al[0]); A1 = -expf(al[1]); A2 = -expf(al[2]); A3 = -expf(al[3]);
  }
  const size_t cr = ((size_t)seg*DI + d)*SEQL;
  const float* dtr = dtT + cr;
  const float* xcr = xcT + cr;
  const float* zr  = zT  + cr;
  float* yor = yoT + cr;
  const float* Bp = Bmg + (size_t)seg*SEQL*DS + s0;
  const float* Cp = Cmg + (size_t)seg*SEQL*DS + s0;
  float h0=0,h1=0,h2=0,h3=0,p0=1,p1=1,p2=1,p3=1;
  const int tb = c << 5;
  for (int tq=0; tq<8; tq++){
    const int t4 = tb + (tq<<2);
    float4 dt4 = *(const float4*)(dtr + t4);
    const float* dtp4 = (const float*)&dt4;
    float4 xc4 = *(const float4*)(xcr + t4);
    const float* xcp4 = (const float*)&xc4;
#pragma unroll
    for (int u=0; u<4; u++){
      float ldt = dtp4[u], lxc = xcp4[u];
      float4 B4 = *(const float4*)(Bp + (size_t)(t4+u)*DS);
      float uu = ldt*lxc;
      float e;
      e = __expf(ldt*A0); h0 = fmaf(e,h0,uu*B4.x); p0*=e;
      e = __expf(ldt*A1); h1 = fmaf(e,h1,uu*B4.y); p1*=e;
      e = __expf(ldt*A2); h2 = fmaf(e,h2,uu*B4.z); p2*=e;
      e = __expf(ldt*A3); h3 = fmaf(e,h3,uu*B4.w); p3*=e;
    }
  }
  hl[c][s0]=h0; hl[c][s0+1]=h1; hl[c][s0+2]=h2; hl[c][s0+3]=h3;
  pl[c][s0]=p0; pl[c][s0+1]=p1; pl[c][s0+2]=p2; pl[c][s0+3]=p3;
  __syncthreads();
  if (tid < 32){
    float H = 0.f;
    Hi[0][tid] = 0.f;
    for (int cc=1; cc<16; cc++){
      H = fmaf(pl[cc-1][tid], H, hl[cc-1][tid]);
      Hi[cc][tid] = H;
    }
  }
  __syncthreads();
  h0=Hi[c][s0]; h1=Hi[c][s0+1]; h2=Hi[c][s0+2]; h3=Hi[c][s0+3];
  const float dsk = dskl[dir*DI + d];
  for (int tq=0; tq<8; tq++){
    const int t4 = tb + (tq<<2);
    float4 dt4 = *(const float4*)(dtr + t4);
    const float* dtp4 = (const float*)&dt4;
    float4 xc4 = *(const float4*)(xcr + t4);
    const float* xcp4 = (const float*)&xc4;
    float4 z4 = *(const float4*)(zr + t4);
    const float* zp4 = (const float*)&z4;
    float yv[4];
#pragma unroll
    for (int u=0; u<4; u++){
      float ldt = dtp4[u], lxc = xcp4[u];
      float4 B4 = *(const float4*)(Bp + (size_t)(t4+u)*DS);
      float4 C4 = *(const float4*)(Cp + (size_t)(t4+u)*DS);
      float uu = ldt*lxc;
      float e;
      e = __expf(ldt*A0); h0 = fmaf(e,h0,uu*B4.x);
      e = __expf(ldt*A1); h1 = fmaf(e,h1,uu*B4.y);
      e = __expf(ldt*A2); h2 = fmaf(e,h2,uu*B4.z);
      e = __expf(ldt*A3); h3 = fmaf(e,h3,uu*B4.w);
      float y = h0*C4.x + h1*C4.y + h2*C4.z + h3*C4.w;
      y += __shfl_xor(y,1); y += __shfl_xor(y,2); y += __shfl_xor(y,4);
      float z = zp4[u];
      yv[u] = fmaf(dsk, lxc, y) * (z * sigmoid_fast(z));
    }
    if (sg==0) *(float4*)(yor + t4) = make_float4(yv[0],yv[1],yv[2],yv[3]);
  }
}

// ---------------------------------------------------------------- yo transpose -> time-major bf16 hi/lo
__global__ __launch_bounds__(256) void k_yotm(const float* __restrict__ yoT,
                                              ushort_t* __restrict__ ytmh,
                                              ushort_t* __restrict__ ytml){
  __shared__ float tl[32][65];
  const int tid = threadIdx.x;
  const int d0 = blockIdx.x << 5;     // 0..512 (17 tiles of 32)
  const int t0 = blockIdx.y << 6;     // 8 tiles of 64
  const int seg = blockIdx.z;
  const int ty = tid >> 4, tx = tid & 15;
#pragma unroll
  for (int p=0; p<2; p++){
    int d = p*16 + ty;
    float4 v = *(const float4*)(yoT + ((size_t)(seg*DI + d0 + d))*SEQL + t0 + tx*4);
    tl[d][tx*4+0]=v.x; tl[d][tx*4+1]=v.y; tl[d][tx*4+2]=v.z; tl[d][tx*4+3]=v.w;
  }
  __syncthreads();
  const int tloc = tid >> 2, dq = (tid & 3) << 3;
  ushort_t h[8], l[8];
#pragma unroll
  for (int j=0;j<8;j++) bf16split(tl[dq+j][tloc], h[j], l[j]);
  uint4 ph, pl4;
  ph.x = (unsigned)h[0] | ((unsigned)h[1]<<16);
  ph.y = (unsigned)h[2] | ((unsigned)h[3]<<16);
  ph.z = (unsigned)h[4] | ((unsigned)h[5]<<16);
  ph.w = (unsigned)h[6] | ((unsigned)h[7]<<16);
  pl4.x = (unsigned)l[0] | ((unsigned)l[1]<<16);
  pl4.y = (unsigned)l[2] | ((unsigned)l[3]<<16);
  pl4.z = (unsigned)l[4] | ((unsigned)l[5]<<16);
  pl4.w = (unsigned)l[6] | ((unsigned)l[7]<<16);
  size_t base = ((size_t)(seg*SEQL + t0 + tloc))*DI + d0 + dq;
  *(uint4*)(ytmh + base) = ph;
  *(uint4*)(ytml + base) = pl4;
}

// ---------------------------------------------------------------- out_proj: split-bf16 MFMA GEMM
__global__ __launch_bounds__(256) void k_gout(
  const ushort_t* __restrict__ ath, const ushort_t* __restrict__ atl,
  const ushort_t* __restrict__ wh,  const ushort_t* __restrict__ wl,
  float* __restrict__ y12)
{
  const int tid = threadIdx.x;
  const int wv = tid >> 6, lane = tid & 63;
  const int m16 = lane & 15, quad = lane >> 4;
  const int q8 = quad << 3;
  const int m0 = blockIdx.x << 6;     // 0..960 (rows within dir)
  const int dir = blockIdx.z;
  const int nloc = (blockIdx.y << 6) + (wv<<4) + m16;   // 0..319
  const bool nval = nloc < DM;
  const int nrow = dir*DM + (nval ? nloc : (DM-1));
  const int bseg = m0 >> 9;
  const int tr0 = m0 & 511;
  const int seg = dir*NB + bseg;
  const ushort_t* bhp = wh + (size_t)nrow*DI + q8;
  const ushort_t* blp = wl + (size_t)nrow*DI + q8;
  const ushort_t* ahp = ath + ((size_t)(seg*SEQL) + tr0 + m16)*DI + q8;
  const ushort_t* alp = atl + ((size_t)(seg*SEQL) + tr0 + m16)*DI + q8;
  fx4 acc[4];
#pragma unroll
  for (int mt=0;mt<4;mt++) acc[mt] = (fx4){0.f,0.f,0.f,0.f};
  for (int k0=0;k0<DI;k0+=32){
    bx8 bh = *(const bx8*)(bhp + k0);
    bx8 bl = *(const bx8*)(blp + k0);
#pragma unroll
    for (int mt=0;mt<4;mt++){
      bx8 ah = *(const bx8*)(ahp + (size_t)mt*16*DI + k0);
      bx8 al = *(const bx8*)(alp + (size_t)mt*16*DI + k0);
      acc[mt] = __builtin_amdgcn_mfma_f32_16x16x32_bf16(ah, bh, acc[mt], 0,0,0);
      acc[mt] = __builtin_amdgcn_mfma_f32_16x16x32_bf16(al, bh, acc[mt], 0,0,0);
      acc[mt] = __builtin_amdgcn_mfma_f32_16x16x32_bf16(ah, bl, acc[mt], 0,0,0);
    }
  }
  if (nval){
#pragma unroll
    for (int mt=0;mt<4;mt++){
#pragma unroll
      for (int r=0;r<4;r++){
        int rg = m0 + mt*16 + quad*4 + r;
        int b = rg >> 9, t = rg & 511;
        int ts = dir ? (511 - t) : t;
        y12[(size_t)dir*ROWS*DM + ((size_t)(b*SEQL + ts))*DM + nloc] = acc[mt][r];
      }
    }
  }
}

// ---------------------------------------------------------------- combine: lam, rmsnorm, residual, next xn
__global__ __launch_bounds__(256) void k_combine(
  const float* __restrict__ y12, const float* __restrict__ lamq,
  const float* __restrict__ n2w, float* __restrict__ xb,
  const float* __restrict__ n1wn, ushort_t* __restrict__ xnh, ushort_t* __restrict__ xnl,
  float lam_init, float omli)
{
  __shared__ float sred[4];
  const int tid = threadIdx.x;
  const int r = blockIdx.x;
  const float* y1 = y12 + (size_t)r*DM;
  const float* y2 = y12 + (size_t)ROWS*DM + (size_t)r*DM;
  float lp = lamq[tid];
  if (tid < 16) lp += lamq[tid+256];
  float lsum = block_reduce_256(lp, sred, tid);
  float lam = sigmoid_fast(lsum) + lam_init;
  float a0 = y1[tid] - lam*y2[tid];
  float a1 = 0.f;
  if (tid<16) a1 = y1[tid+256] - lam*y2[tid+256];
  float ss = block_reduce_256(a0*a0 + a1*a1, sred, tid);
  float rms = rsqrtf(ss*(1.f/DM) + 1e-5f);
  float xo0 = xb[(size_t)r*DM + tid] + a0*rms*n2w[tid]*omli;
  float xo1 = 0.f;
  if (tid<16) xo1 = xb[(size_t)r*DM + tid+256] + a1*rms*n2w[tid+256]*omli;
  xb[(size_t)r*DM+tid] = xo0;
  if (tid<16) xb[(size_t)r*DM+tid+256] = xo1;
  float ss2 = block_reduce_256(xo0*xo0 + xo1*xo1, sred, tid);
  float ivn = rsqrtf(ss2*(1.f/DM) + 1e-5f);
  {
    ushort_t h,l; bf16split(xo0*ivn*n1wn[tid], h, l);
    xnh[(size_t)r*KP + tid] = h; xnl[(size_t)r*KP + tid] = l;
  }
  if (tid < 16){
    ushort_t h,l; bf16split(xo1*ivn*n1wn[tid+256], h, l);
    xnh[(size_t)r*KP + tid+256] = h; xnl[(size_t)r*KP + tid+256] = l;
    xnh[(size_t)r*KP + DM + tid] = 0; xnl[(size_t)r*KP + DM + tid] = 0;
  }
}

// ---------------------------------------------------------------- head
__global__ __launch_bounds__(256) void k_head1(const float* __restrict__ xb, float* __restrict__ xmp){
  int ch = blockIdx.x, b = blockIdx.y, tid = threadIdx.x;
  int t0 = ch*64;
  float s0=0.f, s1=0.f;
  for (int t=t0; t<t0+64; t++){
    const float* row = xb + (size_t)(b*SEQL+t)*DM;
    s0 += row[tid];
    if (tid<16) s1 += row[tid+256];
  }
  xmp[(size_t)(b*8+ch)*DM + tid] = s0;
  if (tid<16) xmp[(size_t)(b*8+ch)*DM + tid+256] = s1;
}

__global__ __launch_bounds__(256) void k_head2(
  const float* __restrict__ xmp, const float* __restrict__ yin,
  const float* __restrict__ mlpw, const float* __restrict__ mlpb,
  const float* __restrict__ pw, const float* __restrict__ pb,
  float* __restrict__ out)
{
  __shared__ float xm[2][DM];
  __shared__ float x2s[2][DM];
  __shared__ float sred[4];
  int tid = threadIdx.x;
  for (int idx=tid; idx<2*DM; idx+=256){
    int b = idx / DM, c = idx - b*DM;
    float s=0.f;
    for (int ch=0; ch<8; ch++) s += xmp[(size_t)(b*8+ch)*DM + c];
    xm[b][c] = s * (1.f/SEQL);
  }
  __syncthreads();
  for (int idx=tid; idx<2*DM; idx+=256){
    int b = idx / DM, c = idx - b*DM;
    float acc = mlpb[c];
    const float* wr = mlpw + (size_t)c*DM;
    for (int k=0;k<DM;k++) acc += wr[k]*xm[b][k];
    float v = fmaxf(acc, 0.f);
    x2s[b][c] = v;
    out[2 + b*DM + c] = v;
  }
  __syncthreads();
  for (int b=0;b<2;b++){
    float p = x2s[b][tid]*pw[tid];
    if (tid<16) p += x2s[b][tid+256]*pw[tid+256];
    float tot = block_reduce_256(p, sred, tid);
    if (tid==0) out[b] = tot + yin[b]*pw[DM] + pb[0];
  }
}

// ----------------------------------------------------------------
extern "C" void kernel_launch(void* const* d_in, const int* in_sizes, int n_in,
                              void* d_out, int out_size, void* d_ws, size_t ws_size,
                              hipStream_t stream)
{
  const float* x0     = (const float*)d_in[0];
  const float* yin    = (const float*)d_in[1];
  const float* in_w   = (const float*)d_in[2];
  const float* conv_w = (const float*)d_in[3];
  const float* conv_b = (const float*)d_in[4];
  const float* x_w    = (const float*)d_in[5];
  const float* dt_w   = (const float*)d_in[6];
  const float* dt_b   = (const float*)d_in[7];
  const float* a_log  = (const float*)d_in[8];
  const float* dskip  = (const float*)d_in[9];
  const float* out_w  = (const float*)d_in[10];
  const float* lamq   = (const float*)d_in[11];
  const float* n1w    = (const float*)d_in[12];
  const float* n2w    = (const float*)d_in[13];
  const float* mlpw   = (const float*)d_in[14];
  const float* mlpb   = (const float*)d_in[15];
  const float* pw     = (const float*)d_in[16];
  const float* pb     = (const float*)d_in[17];

  float* ws  = (float*)d_ws;
  float* xb  = ws + OFF_X;
  float* xz  = ws + OFF_XZ;
  float* xcT = ws + OFF_XCT;
  float* dtT = ws + OFF_DTT;
  float* zT  = ws + OFF_ZT;
  float* Bm  = ws + OFF_BM;
  float* Cm  = ws + OFF_CM;
  float* yoT = ws + OFF_YOT;
  float* y12 = ws + OFF_Y12;
  float* xmp = ws + OFF_XMP;
  float* dtwT= ws + OFF_DTWT;
  ushort_t* xnh  = (ushort_t*)(ws + OFF_XNH);
  ushort_t* xnl  = (ushort_t*)(ws + OFF_XNL);
  ushort_t* ytmh = (ushort_t*)(ws + OFF_YTMH);
  ushort_t* ytml = (ushort_t*)(ws + OFF_YTML);
  ushort_t* winh = (ushort_t*)(ws + OFF_WINH);
  ushort_t* winl = (ushort_t*)(ws + OFF_WINL);
  ushort_t* wouth= (ushort_t*)(ws + OFF_WOUTH);
  ushort_t* woutl= (ushort_t*)(ws + OFF_WOUTL);
  float* outp = (float*)d_out;

  k_convw<<<(NINW + NOUTW + 255)/256, 256, 0, stream>>>(in_w, out_w, winh, winl, wouth, woutl);
  k_transpose<<<(24*544*DTR + 255)/256, 256, 0, stream>>>(dt_w, dtwT);
  k_init<<<ROWS, 64, 0, stream>>>(x0, n1w, xb, xnh, xnl);
  for (int i=0;i<NL;i++){
    float lam_init = 0.8f - 0.6f*expf(-0.3f*(float)i);
    k_gin<<<dim3(16,34), 256, 0, stream>>>(xnh, xnl,
        winh + (size_t)i*2176*KP, winl + (size_t)i*2176*KP, xz);
    k_xdt<<<256, 512, 0, stream>>>(xz,
        conv_w + (size_t)i*2*DI*4, conv_b + (size_t)i*2*DI,
        x_w + (size_t)i*2*81*DI, dtwT + (size_t)i*2*DTR*DI, dt_b + (size_t)i*2*DI,
        xcT, dtT, zT, Bm, Cm);
    k_scan<<<dim3(DI,NB,2), 128, 0, stream>>>(dtT, xcT, Bm, Cm,
        a_log + (size_t)i*2*DI*DS, dskip + (size_t)i*2*DI, zT, yoT);
    k_yotm<<<dim3(17,8,4), 256, 0, stream>>>(yoT, ytmh, ytml);
    k_gout<<<dim3(16,5,2), 256, 0, stream>>>(ytmh, ytml,
        wouth + (size_t)i*544*544, woutl + (size_t)i*544*544, y12);
    k_combine<<<ROWS, 256, 0, stream>>>(y12, lamq + (size_t)i*DM, n2w + (size_t)i*DM,
        xb, n1w + (size_t)((i+1)%NL)*DM, xnh, xnl, lam_init, 1.f - lam_init);
  }
  k_head1<<<dim3(8,2), 256, 0, stream>>>(xb, xmp);
  k_head2<<<1, 256, 0, stream>>>(xmp, yin, mlpw, mlpb, pw, pb, outp);
}